// Round 3
// baseline (23.714 us; speedup 1.0000x reference)
//
#include <hip/hip_runtime.h>
#include <hip/hip_bf16.h>

constexpr int Bn = 4096;
constexpr int Dn = 128;
constexpr int Cn = 256;
constexpr int Np = Cn + Dn;   // 384 augmented cols (256 S + 128 H)
constexpr int PADB = 130;     // bf16 elems per LDS row (bank spread, keeps u32 align)

typedef __attribute__((ext_vector_type(8))) short bf16x8;  // 8 bf16 = 4 VGPR
typedef __attribute__((ext_vector_type(4))) float f32x4;

static __device__ inline unsigned short f2bfu(float f) {
    __hip_bfloat16 h = __float2bfloat16(f);
    return *reinterpret_cast<unsigned short*>(&h);
}
static __device__ inline float bfu2f(unsigned short u) {
    __hip_bfloat16 h = *reinterpret_cast<__hip_bfloat16*>(&u);
    return __bfloat162float(h);
}
static __device__ inline short f2bf(float f) {
    __hip_bfloat16 h = __float2bfloat16(f);
    return *reinterpret_cast<short*>(&h);
}

// 64 blocks x 256 threads. Block b: S-cols c0..c0+3 and H-cols dc0, dc0+1.
// LDS-staged bf16 alpha, symmetrized in place; G accumulated fp32; t fp32.
__global__ __launch_bounds__(256) void setup_kernel(
    const float* __restrict__ means, const float* __restrict__ alpha,
    __hip_bfloat16* __restrict__ Gt, float* __restrict__ tvec) {
    __shared__ unsigned short albf[Dn * PADB];   // 33,280 B
    __shared__ float mc[4][Dn];                  // 2 KB
    __shared__ float gred[4][4][Dn];             // 8 KB
    __shared__ float red2[4][2];
    const int tid = threadIdx.x;
    const int blk = blockIdx.x;       // 0..63
    const int c0 = blk * 4;
    const int dc0 = blk * 2;

    // Phase 1: stage bf16(alpha) into albf[d][e] (coalesced float4 reads)
    #pragma unroll
    for (int p = 0; p < 16; ++p) {
        int idx4 = p * 256 + tid;            // float4 index 0..4095
        int d = idx4 >> 5;                   // 32 float4 per row
        int e0 = (idx4 & 31) << 2;
        float4 v = ((const float4*)alpha)[idx4];
        unsigned int lo = f2bfu(v.x) | ((unsigned int)f2bfu(v.y) << 16);
        unsigned int hi = f2bfu(v.z) | ((unsigned int)f2bfu(v.w) << 16);
        unsigned int* wp = (unsigned int*)&albf[d * PADB + e0];  // e0 even -> aligned
        wp[0] = lo; wp[1] = hi;
    }
    // Phase 2: means columns c0..c0+3 (one 16B gather per row)
    if (tid < Dn) {
        float4 v = *(const float4*)&means[tid * Cn + c0];
        mc[0][tid] = v.x; mc[1][tid] = v.y; mc[2][tid] = v.z; mc[3][tid] = v.w;
    }
    __syncthreads();

    // Phase 3: in-place symmetrize: albf[d][e] <- bf16(a[d][e]+a[e][d]).
    // Pair (d<e) owner reads+writes both triangle elements; (d>e) threads skip.
    // Each LDS location is touched by exactly one thread -> race-free.
    for (int i = 0; i < 64; ++i) {
        int idx = i * 256 + tid;
        int d = idx >> 7, e = idx & 127;
        if (d < e) {
            float a = bfu2f(albf[d * PADB + e]);
            float b = bfu2f(albf[e * PADB + d]);
            unsigned short s = f2bfu(a + b);
            albf[d * PADB + e] = s;
            albf[e * PADB + d] = s;
        } else if (d == e) {
            float a = bfu2f(albf[d * PADB + e]);
            albf[d * PADB + e] = f2bfu(a + a);
        }
    }
    __syncthreads();

    // Phase 4: G[d][c] = sum_e asum[d][e]*m[e][c]  (asum symmetric: read [e][d])
    // thread = (d-pair dp, e-quarter eq); 1 packed u32 read + 4 broadcasts per 8 FMA
    const int dp = tid & 63, eq = tid >> 6;
    const int d0 = 2 * dp;
    float g[2][4] = {};
    for (int e = eq * 32; e < eq * 32 + 32; ++e) {
        unsigned int pair = *(const unsigned int*)&albf[e * PADB + d0];
        float s0 = bfu2f((unsigned short)(pair & 0xffffu));
        float s1 = bfu2f((unsigned short)(pair >> 16));
        #pragma unroll
        for (int cc = 0; cc < 4; ++cc) {
            float m = mc[cc][e];
            g[0][cc] = fmaf(s0, m, g[0][cc]);
            g[1][cc] = fmaf(s1, m, g[1][cc]);
        }
    }
    #pragma unroll
    for (int cc = 0; cc < 4; ++cc) {
        gred[eq][cc][d0]     = g[0][cc];
        gred[eq][cc][d0 + 1] = g[1][cc];
    }
    __syncthreads();

    // Phase 5a: Asym passthrough (all 256 threads): Gt[(256+dc)][e] = 0.5*asum[e][dc]
    {
        int dcj = tid >> 7, e = tid & 127;
        int dc = dc0 + dcj;
        float v = 0.5f * bfu2f(albf[e * PADB + dc]);
        Gt[(Cn + dc) * Dn + e] = __float2bfloat16(v);
    }
    // Phase 5b: reduce G over e-quarters, write Gt, fp32 t
    if (tid < Dn) {
        const int d = tid;
        const int lane = tid & 63, wv = tid >> 6;   // waves 0,1
        #pragma unroll
        for (int cc = 0; cc < 4; ++cc) {
            float Gf = gred[0][cc][d] + gred[1][cc][d] + gred[2][cc][d] + gred[3][cc][d];
            Gt[(c0 + cc) * Dn + d] = __float2bfloat16(Gf);
            float p = mc[cc][d] * Gf;
            #pragma unroll
            for (int off = 32; off > 0; off >>= 1) p += __shfl_down(p, off);
            if (lane == 0) red2[cc][wv] = p;
        }
    }
    __syncthreads();
    if (tid < 4) tvec[c0 + tid] = 0.5f * (red2[tid][0] + red2[tid][1]);
}

// 256 blocks x 768 threads (12 waves, 3/SIMD). Block = 16 rows of X.
// Wave w owns cols [32w, 32w+32) of the augmented [X*Gt'] product:
// w<8 -> S-cols (min epilogue), w>=8 -> H-cols (xax epilogue).
__global__ __launch_bounds__(768) void main_kernel(
    const float* __restrict__ X, const __hip_bfloat16* __restrict__ Gt,
    const float* __restrict__ tvec, float* __restrict__ out) {
    const int tid = threadIdx.x;
    const int w = tid >> 6;          // 0..11
    const int lane = tid & 63;
    const int l15 = lane & 15;
    const int lh = lane >> 4;        // 0..3
    const int b0 = blockIdx.x * 16;

    __shared__ float smin[8][16];
    __shared__ float sxax[4][16];

    // A fragments: A[row=l15][k=32k0+8lh+i]
    bf16x8 af[4];
    const float* xrow = X + (b0 + l15) * Dn;
    #pragma unroll
    for (int k0 = 0; k0 < 4; ++k0) {
        const float4* p = (const float4*)(xrow + 32 * k0 + 8 * lh);
        float4 x0 = p[0], x1 = p[1];
        bf16x8 a;
        a[0] = f2bf(x0.x); a[1] = f2bf(x0.y); a[2] = f2bf(x0.z); a[3] = f2bf(x0.w);
        a[4] = f2bf(x1.x); a[5] = f2bf(x1.y); a[6] = f2bf(x1.z); a[7] = f2bf(x1.w);
        af[k0] = a;
    }

    // B fragments: col = 32w + 16tt + l15 (unified S/H range), col-major Gt
    bf16x8 bfr[2][4];
    #pragma unroll
    for (int tt = 0; tt < 2; ++tt) {
        const int col = 32 * w + 16 * tt + l15;
        const __hip_bfloat16* gcol = Gt + col * Dn;
        #pragma unroll
        for (int k0 = 0; k0 < 4; ++k0)
            bfr[tt][k0] = *(const bf16x8*)(gcol + 32 * k0 + 8 * lh);
    }

    f32x4 acc[2];
    #pragma unroll
    for (int tt = 0; tt < 2; ++tt) acc[tt] = (f32x4){0.f, 0.f, 0.f, 0.f};

    #pragma unroll
    for (int k0 = 0; k0 < 4; ++k0)
        #pragma unroll
        for (int tt = 0; tt < 2; ++tt)
            acc[tt] = __builtin_amdgcn_mfma_f32_16x16x32_bf16(
                af[k0], bfr[tt][k0], acc[tt], 0, 0, 0);

    // C layout: col = lane&15, row = 4*(lane>>4) + reg
    if (w < 8) {
        float mr[4];
        #pragma unroll
        for (int r = 0; r < 4; ++r) mr[r] = 1e30f;
        #pragma unroll
        for (int tt = 0; tt < 2; ++tt) {
            float tc = tvec[32 * w + 16 * tt + l15];
            #pragma unroll
            for (int r = 0; r < 4; ++r) mr[r] = fminf(mr[r], tc - acc[tt][r]);
        }
        #pragma unroll
        for (int r = 0; r < 4; ++r)
            #pragma unroll
            for (int m = 1; m < 16; m <<= 1)
                mr[r] = fminf(mr[r], __shfl_xor(mr[r], m));
        if (l15 == 0)
            #pragma unroll
            for (int r = 0; r < 4; ++r) smin[w][4 * lh + r] = mr[r];
    } else {
        float p[4] = {0.f, 0.f, 0.f, 0.f};
        #pragma unroll
        for (int tt = 0; tt < 2; ++tt) {
            const int d = 32 * (w - 8) + 16 * tt + l15;
            #pragma unroll
            for (int r = 0; r < 4; ++r) {
                const int row = 4 * lh + r;
                p[r] = fmaf(acc[tt][r], X[(b0 + row) * Dn + d], p[r]);
            }
        }
        #pragma unroll
        for (int r = 0; r < 4; ++r)
            #pragma unroll
            for (int m = 1; m < 16; m <<= 1)
                p[r] += __shfl_xor(p[r], m);
        if (l15 == 0)
            #pragma unroll
            for (int r = 0; r < 4; ++r) sxax[w - 8][4 * lh + r] = p[r];
    }
    __syncthreads();

    if (tid < 16) {
        float mn = fminf(fminf(fminf(smin[0][tid], smin[1][tid]),
                               fminf(smin[2][tid], smin[3][tid])),
                         fminf(fminf(smin[4][tid], smin[5][tid]),
                               fminf(smin[6][tid], smin[7][tid])));
        float xa = sxax[0][tid] + sxax[1][tid] + sxax[2][tid] + sxax[3][tid];
        out[b0 + tid] = xa + mn;
    }
}

extern "C" void kernel_launch(void* const* d_in, const int* in_sizes, int n_in,
                              void* d_out, int out_size, void* d_ws, size_t ws_size,
                              hipStream_t stream) {
    const float* X     = (const float*)d_in[0];
    const float* means = (const float*)d_in[1];
    const float* alpha = (const float*)d_in[2];
    float* out = (float*)d_out;
    __hip_bfloat16* Gt = (__hip_bfloat16*)d_ws;                            // [Np*Dn]
    float* tvec = (float*)((char*)d_ws + Np * Dn * sizeof(__hip_bfloat16)); // [Cn]

    setup_kernel<<<64, 256, 0, stream>>>(means, alpha, Gt, tvec);
    main_kernel<<<Bn / 16, 768, 0, stream>>>(X, Gt, tvec, out);
}

// Round 4
// 22.294 us; speedup vs baseline: 1.0637x; 1.0637x over previous
//
#include <hip/hip_runtime.h>
#include <hip/hip_bf16.h>

constexpr int Bn = 4096;
constexpr int Dn = 128;
constexpr int Cn = 256;
constexpr int Np = Cn + Dn;   // 384 augmented cols (256 S + 128 H)

typedef __attribute__((ext_vector_type(8))) short bf16x8;  // 8 bf16 = 4 VGPR
typedef __attribute__((ext_vector_type(4))) float f32x4;

static __device__ inline short f2bf(float f) {
    __hip_bfloat16 h = __float2bfloat16(f);
    return *reinterpret_cast<short*>(&h);
}

// One block per row d (128 blocks x 256 threads, thread <-> column c).
//   asym[d][:] staged once in LDS (uniform broadcast reads in the loop).
//   G[d][c] = sum_e asym[d][e] * means[e][c]   (fp32 accumulate)
//   Gt[c*Dn+d]       = bf16(G[d][c])           (S-cols, col-major for main's B-frags)
//   Gt[(Cn+d)*Dn+e]  = bf16(0.5*asym[d][e])    (H-cols)
//   tvec[c]         += 0.5 * means[d][c] * G[d][c]   (fp32 atomics; tvec pre-zeroed)
__global__ __launch_bounds__(256) void setup_kernel(
    const float* __restrict__ means, const float* __restrict__ alpha,
    __hip_bfloat16* __restrict__ Gt, float* __restrict__ tvec) {
    const int d = blockIdx.x;    // 0..127
    const int c = threadIdx.x;   // 0..255
    __shared__ float asrow[Dn];

    if (c < Dn) {
        // row read coalesced; column read is a single stride-512B gather (once)
        asrow[c] = alpha[d * Dn + c] + alpha[c * Dn + d];
        Gt[(Cn + d) * Dn + c] = __float2bfloat16(0.5f * asrow[c]);
    }
    __syncthreads();

    float g = 0.f;
    #pragma unroll 8
    for (int e = 0; e < Dn; ++e)
        g = fmaf(asrow[e], means[e * Cn + c], g);   // LDS broadcast x coalesced load

    Gt[c * Dn + d] = __float2bfloat16(g);
    atomicAdd(&tvec[c], 0.5f * means[d * Cn + c] * g);
}

// One block = 16 rows of X, 6 waves. Waves 0-3: S-cols (min epilogue),
// waves 4-5: H-cols (xax epilogue). K=128 -> 4 MFMA steps per tile, 4 tiles/wave.
__global__ __launch_bounds__(384) void main_kernel(
    const float* __restrict__ X, const __hip_bfloat16* __restrict__ Gt,
    const float* __restrict__ tvec, float* __restrict__ out) {
    const int tid = threadIdx.x;
    const int w = tid >> 6;          // wave 0..5
    const int lane = tid & 63;
    const int l15 = lane & 15;
    const int lh = lane >> 4;        // 0..3
    const int b0 = blockIdx.x * 16;

    __shared__ float smin[4][16];
    __shared__ float sxax[2][16];

    // ---- A fragments (shared geometry across waves): A[row=l15][k=32k0+8lh+i]
    bf16x8 af[4];
    const float* xrow = X + (b0 + l15) * Dn;
    #pragma unroll
    for (int k0 = 0; k0 < 4; ++k0) {
        const float4* p = (const float4*)(xrow + 32 * k0 + 8 * lh);
        float4 x0 = p[0], x1 = p[1];
        bf16x8 a;
        a[0] = f2bf(x0.x); a[1] = f2bf(x0.y); a[2] = f2bf(x0.z); a[3] = f2bf(x0.w);
        a[4] = f2bf(x1.x); a[5] = f2bf(x1.y); a[6] = f2bf(x1.z); a[7] = f2bf(x1.w);
        af[k0] = a;
    }

    // ---- B fragments: B[k=32k0+8lh+i][col] = Gt[col*Dn + k]  (col-major storage)
    bf16x8 bfr[4][4];
    #pragma unroll
    for (int tt = 0; tt < 4; ++tt) {
        const int col = 64 * w + 16 * tt + l15;
        const __hip_bfloat16* gcol = Gt + col * Dn;
        #pragma unroll
        for (int k0 = 0; k0 < 4; ++k0)
            bfr[tt][k0] = *(const bf16x8*)(gcol + 32 * k0 + 8 * lh);
    }

    f32x4 acc[4];
    #pragma unroll
    for (int tt = 0; tt < 4; ++tt) acc[tt] = (f32x4){0.f, 0.f, 0.f, 0.f};

    #pragma unroll
    for (int k0 = 0; k0 < 4; ++k0)
        #pragma unroll
        for (int tt = 0; tt < 4; ++tt)
            acc[tt] = __builtin_amdgcn_mfma_f32_16x16x32_bf16(
                af[k0], bfr[tt][k0], acc[tt], 0, 0, 0);

    // C layout (verified): col = lane&15, row = 4*(lane>>4) + reg
    if (w < 4) {
        // min over this wave's 64 S-columns of (t[c] - S[b,c])
        float mr[4];
        #pragma unroll
        for (int r = 0; r < 4; ++r) mr[r] = 1e30f;
        #pragma unroll
        for (int tt = 0; tt < 4; ++tt) {
            float tc = tvec[64 * w + 16 * tt + l15];
            #pragma unroll
            for (int r = 0; r < 4; ++r) mr[r] = fminf(mr[r], tc - acc[tt][r]);
        }
        #pragma unroll
        for (int r = 0; r < 4; ++r)
            #pragma unroll
            for (int m = 1; m < 16; m <<= 1)
                mr[r] = fminf(mr[r], __shfl_xor(mr[r], m));
        if (l15 == 0)
            #pragma unroll
            for (int r = 0; r < 4; ++r) smin[w][4 * lh + r] = mr[r];
    } else {
        // xax partial: sum_d X[row,d] * H[row,d] over this wave's 64 d-columns
        float p[4] = {0.f, 0.f, 0.f, 0.f};
        #pragma unroll
        for (int tt = 0; tt < 4; ++tt) {
            const int d = 64 * (w - 4) + 16 * tt + l15;
            #pragma unroll
            for (int r = 0; r < 4; ++r) {
                const int row = 4 * lh + r;
                p[r] = fmaf(acc[tt][r], X[(b0 + row) * Dn + d], p[r]);
            }
        }
        #pragma unroll
        for (int r = 0; r < 4; ++r)
            #pragma unroll
            for (int m = 1; m < 16; m <<= 1)
                p[r] += __shfl_xor(p[r], m);
        if (l15 == 0)
            #pragma unroll
            for (int r = 0; r < 4; ++r) sxax[w - 4][4 * lh + r] = p[r];
    }
    __syncthreads();

    if (tid < 16) {
        float mn = fminf(fminf(smin[0][tid], smin[1][tid]),
                         fminf(smin[2][tid], smin[3][tid]));
        out[b0 + tid] = sxax[0][tid] + sxax[1][tid] + mn;
    }
}

extern "C" void kernel_launch(void* const* d_in, const int* in_sizes, int n_in,
                              void* d_out, int out_size, void* d_ws, size_t ws_size,
                              hipStream_t stream) {
    const float* X     = (const float*)d_in[0];
    const float* means = (const float*)d_in[1];
    const float* alpha = (const float*)d_in[2];
    float* out = (float*)d_out;
    __hip_bfloat16* Gt = (__hip_bfloat16*)d_ws;                             // [Np*Dn]
    float* tvec = (float*)((char*)d_ws + Np * Dn * sizeof(__hip_bfloat16)); // [Cn]

    hipMemsetAsync(tvec, 0, Cn * sizeof(float), stream);   // atomics target
    setup_kernel<<<Dn, 256, 0, stream>>>(means, alpha, Gt, tvec);
    main_kernel<<<Bn / 16, 384, 0, stream>>>(X, Gt, tvec, out);
}

// Round 5
// 17.447 us; speedup vs baseline: 1.3592x; 1.2778x over previous
//
#include <hip/hip_runtime.h>
#include <hip/hip_bf16.h>

constexpr int Bn = 4096;
constexpr int Dn = 128;
constexpr int Cn = 256;

typedef __attribute__((ext_vector_type(8))) short bf16x8;  // 8 bf16 = 4 VGPR
typedef __attribute__((ext_vector_type(4))) float f32x4;

static __device__ inline unsigned short f2bfu(float f) {
    __hip_bfloat16 h = __float2bfloat16(f);
    return *reinterpret_cast<unsigned short*>(&h);
}
static __device__ inline float bfu2f(unsigned short u) {
    __hip_bfloat16 h = *reinterpret_cast<__hip_bfloat16*>(&u);
    return __bfloat162float(h);
}
static __device__ inline unsigned pk2(float x, float y) {
    return (unsigned)f2bfu(x) | ((unsigned)f2bfu(y) << 16);
}

// XOR-swizzled byte offset for 256B-row bf16 tiles (G4 recipe):
//   row-major [R][128] bf16; lane-varying-row b128 reads become conflict-optimal.
#define SWZ_OFF(row, e) ((row) * 256 + ((((e) * 2)) ^ (((row) & 7) << 4)))
#define MN_IDX(d, c)    ((d) * 258 + (c))   // u16 index; 129-word stride (==1 mod 32)

// Single fused kernel: 256 blocks x 512 threads (8 waves), block = 16 rows of X.
// Each block redundantly computes G = asym*means (MFMA) + t, then the main GEMM.
__global__ __launch_bounds__(512) void fused_kernel(
    const float* __restrict__ X, const float* __restrict__ means,
    const float* __restrict__ alpha, float* __restrict__ out) {
    __shared__ __align__(16) unsigned char AL[Dn * 256];      // 32768B: bf16 asym, swizzled
    __shared__ __align__(16) unsigned char MN[Dn * 258 * 2];  // 66048B: bf16 means; later G
    __shared__ float TL[Cn];                                   // t[c]
    __shared__ float SMIN[8][16];
    __shared__ float SXAX[8][16];

    const int tid = threadIdx.x;
    const int w = tid >> 6;          // wave 0..7
    const int lane = tid & 63;
    const int l15 = lane & 15;
    const int lh = lane >> 4;        // 0..3
    const int b0 = blockIdx.x * 16;
    unsigned short* mn16 = (unsigned short*)MN;

    // ---------- Phase A: stage alpha (swizzled) + means (row-major) as bf16 ----------
    {
        const float4* a4 = (const float4*)alpha;
        #pragma unroll
        for (int i = 0; i < 8; ++i) {
            int idx4 = tid + i * 512;            // 0..4095
            int d = idx4 >> 5, e0 = (idx4 & 31) << 2;
            float4 v = a4[idx4];
            unsigned char* p = AL + SWZ_OFF(d, e0);   // e0*2 % 8 == 0 -> 4B aligned
            *(unsigned*)p = pk2(v.x, v.y);
            *(unsigned*)(p + 4) = pk2(v.z, v.w);
        }
        const float4* m4 = (const float4*)means;
        #pragma unroll
        for (int i = 0; i < 16; ++i) {
            int idx4 = tid + i * 512;            // 0..8191
            int d = idx4 >> 6, c0 = (idx4 & 63) << 2;
            unsigned* p = (unsigned*)&mn16[MN_IDX(d, c0)];
            float4 v = m4[idx4];
            p[0] = pk2(v.x, v.y);
            p[1] = pk2(v.z, v.w);
        }
    }
    __syncthreads();

    // ---------- Phase B: symmetrize alpha in place: AL[d][e] <- bf16(a[d][e]+a[e][d]) ----------
    // Pair owner (d<=e) writes both locations; race-free.
    #pragma unroll
    for (int i = 0; i < 32; ++i) {
        int idx = tid + i * 512;
        int d = idx >> 7, e = idx & 127;
        if (d <= e) {
            unsigned short* pde = (unsigned short*)(AL + SWZ_OFF(d, e));
            unsigned short* ped = (unsigned short*)(AL + SWZ_OFF(e, d));
            float s = bfu2f(*pde) + bfu2f(*ped);
            unsigned short sv = f2bfu(s);
            *pde = sv;
            *ped = sv;
        }
    }
    __syncthreads();

    // ---------- Phase C: G-GEMM  G[128x256] = asym * means  (wave w: cols 32w..32w+31) ----------
    f32x4 gacc[2][8];
    #pragma unroll
    for (int j = 0; j < 2; ++j)
        #pragma unroll
        for (int mt = 0; mt < 8; ++mt) gacc[j][mt] = (f32x4){0.f, 0.f, 0.f, 0.f};

    #pragma unroll
    for (int k0 = 0; k0 < 4; ++k0) {
        bf16x8 bj[2];
        #pragma unroll
        for (int j = 0; j < 2; ++j) {
            const int c = 32 * w + 16 * j + l15;
            bf16x8 b;
            #pragma unroll
            for (int i = 0; i < 8; ++i)
                b[i] = (short)mn16[MN_IDX(32 * k0 + 8 * lh + i, c)];  // conflict-free banks
            bj[j] = b;
        }
        #pragma unroll
        for (int mt = 0; mt < 8; ++mt) {
            bf16x8 a = *(const bf16x8*)(AL + SWZ_OFF(16 * mt + l15, 32 * k0 + 8 * lh));
            #pragma unroll
            for (int j = 0; j < 2; ++j)
                gacc[j][mt] = __builtin_amdgcn_mfma_f32_16x16x32_bf16(a, bj[j], gacc[j][mt], 0, 0, 0);
        }
    }

    // ---------- Phase D: t[c] = 0.5 * sum_d m[d][c] * G[d][c]  (from C-regs) ----------
    {
        float tp[2];
        #pragma unroll
        for (int j = 0; j < 2; ++j) {
            const int c = 32 * w + 16 * j + l15;
            float v = 0.f;
            #pragma unroll
            for (int mt = 0; mt < 8; ++mt)
                #pragma unroll
                for (int r = 0; r < 4; ++r)
                    v = fmaf(bfu2f(mn16[MN_IDX(16 * mt + 4 * lh + r, c)]), gacc[j][mt][r], v);
            v += __shfl_xor(v, 16);   // reduce across lh (lanes share l15)
            v += __shfl_xor(v, 32);
            tp[j] = v;
        }
        if (lane < 16) {
            TL[32 * w + lane] = 0.5f * tp[0];
            TL[32 * w + 16 + lane] = 0.5f * tp[1];
        }
    }
    __syncthreads();   // everyone done READING means before overwrite

    // ---------- Phase E: write G (bf16, swizzled col-major [c][d]) into MN region ----------
    #pragma unroll
    for (int j = 0; j < 2; ++j) {
        const int c = 32 * w + 16 * j + l15;
        #pragma unroll
        for (int mt = 0; mt < 8; ++mt)
            #pragma unroll
            for (int r0 = 0; r0 < 4; r0 += 2) {
                const int d = 16 * mt + 4 * lh + r0;          // 2d % 4 == 0 -> u32 ok
                *(unsigned*)(MN + SWZ_OFF(c, d)) =
                    pk2(gacc[j][mt][r0], gacc[j][mt][r0 + 1]);
            }
    }
    __syncthreads();

    // ---------- Phase F: main GEMM [X | augmented] -- wave w: tiles 3w..3w+2 of 24 ----------
    // tiles 0..15: S-cols (G from MN region); tiles 16..23: H-cols (asym from AL).
    bf16x8 af[4];
    {
        const float* xrow = X + (b0 + l15) * Dn;
        #pragma unroll
        for (int k0 = 0; k0 < 4; ++k0) {
            const float4* p = (const float4*)(xrow + 32 * k0 + 8 * lh);
            float4 x0 = p[0], x1 = p[1];
            bf16x8 a;
            a[0] = (short)f2bfu(x0.x); a[1] = (short)f2bfu(x0.y);
            a[2] = (short)f2bfu(x0.z); a[3] = (short)f2bfu(x0.w);
            a[4] = (short)f2bfu(x1.x); a[5] = (short)f2bfu(x1.y);
            a[6] = (short)f2bfu(x1.z); a[7] = (short)f2bfu(x1.w);
            af[k0] = a;
        }
    }
    bf16x8 bf3[3][4];
    #pragma unroll
    for (int j2 = 0; j2 < 3; ++j2) {
        const int tg = 3 * w + j2;
        const unsigned char* base = (tg < 16) ? (const unsigned char*)MN : (const unsigned char*)AL;
        const int rowc = (tg < 16) ? (16 * tg + l15) : (16 * (tg - 16) + l15);
        #pragma unroll
        for (int k0 = 0; k0 < 4; ++k0)
            bf3[j2][k0] = *(const bf16x8*)(base + SWZ_OFF(rowc, 32 * k0 + 8 * lh));
    }
    f32x4 macc[3];
    #pragma unroll
    for (int j2 = 0; j2 < 3; ++j2) macc[j2] = (f32x4){0.f, 0.f, 0.f, 0.f};
    #pragma unroll
    for (int k0 = 0; k0 < 4; ++k0)
        #pragma unroll
        for (int j2 = 0; j2 < 3; ++j2)
            macc[j2] = __builtin_amdgcn_mfma_f32_16x16x32_bf16(af[k0], bf3[j2][k0], macc[j2], 0, 0, 0);

    // epilogue: C layout col=lane&15, row=4*(lane>>4)+reg
    {
        float mr[4], px[4];
        #pragma unroll
        for (int r = 0; r < 4; ++r) { mr[r] = 1e30f; px[r] = 0.f; }
        #pragma unroll
        for (int j2 = 0; j2 < 3; ++j2) {
            const int tg = 3 * w + j2;
            if (tg < 16) {
                float tc = TL[16 * tg + l15];
                #pragma unroll
                for (int r = 0; r < 4; ++r) mr[r] = fminf(mr[r], tc - macc[j2][r]);
            } else {
                const int dp = 16 * (tg - 16) + l15;
                #pragma unroll
                for (int r = 0; r < 4; ++r)
                    px[r] = fmaf(macc[j2][r], X[(b0 + 4 * lh + r) * Dn + dp], px[r]);
            }
        }
        #pragma unroll
        for (int r = 0; r < 4; ++r) {
            #pragma unroll
            for (int m = 1; m < 16; m <<= 1) {
                mr[r] = fminf(mr[r], __shfl_xor(mr[r], m));
                px[r] += __shfl_xor(px[r], m);
            }
        }
        if (l15 == 0) {
            #pragma unroll
            for (int r = 0; r < 4; ++r) {
                SMIN[w][4 * lh + r] = mr[r];
                SXAX[w][4 * lh + r] = px[r];
            }
        }
    }
    __syncthreads();

    if (tid < 16) {
        float mnv = 1e30f, xa = 0.f;
        #pragma unroll
        for (int w8 = 0; w8 < 8; ++w8) {
            mnv = fminf(mnv, SMIN[w8][tid]);
            xa += SXAX[w8][tid];
        }
        out[b0 + tid] = 0.5f * xa + mnv;   // xax = 0.5 * x^T asym x
    }
}

extern "C" void kernel_launch(void* const* d_in, const int* in_sizes, int n_in,
                              void* d_out, int out_size, void* d_ws, size_t ws_size,
                              hipStream_t stream) {
    const float* X     = (const float*)d_in[0];
    const float* means = (const float*)d_in[1];
    const float* alpha = (const float*)d_in[2];
    float* out = (float*)d_out;
    fused_kernel<<<Bn / 16, 512, 0, stream>>>(X, means, alpha, out);
}

// Round 6
// 14.470 us; speedup vs baseline: 1.6388x; 1.2057x over previous
//
#include <hip/hip_runtime.h>
#include <hip/hip_bf16.h>

constexpr int Bn = 4096;
constexpr int Dn = 128;
constexpr int Cn = 256;

typedef __attribute__((ext_vector_type(8))) short bf16x8;  // 8 bf16 = 4 VGPR
typedef __attribute__((ext_vector_type(4))) float f32x4;

static __device__ inline unsigned short f2bfu(float f) {
    __hip_bfloat16 h = __float2bfloat16(f);
    return *reinterpret_cast<unsigned short*>(&h);
}
static __device__ inline float bfu2f(unsigned short u) {
    __hip_bfloat16 h = *reinterpret_cast<__hip_bfloat16*>(&u);
    return __bfloat162float(h);
}
static __device__ inline unsigned pk2(float x, float y) {
    return (unsigned)f2bfu(x) | ((unsigned)f2bfu(y) << 16);
}

// XOR-swizzled byte offset for 256B-row bf16 tiles (G4 recipe):
//   row-major [R][128] bf16; lane-varying-row b128 reads become conflict-optimal.
#define SWZ_OFF(row, e) ((row) * 256 + ((((e) * 2)) ^ (((row) & 7) << 4)))
#define MN_IDX(d, c)    ((d) * 258 + (c))   // u16 index; 129-word stride (==1 mod 32)

// Single fused kernel: 256 blocks x 512 threads (8 waves), block = 16 rows of X.
// Identity used (exact for any alpha except the ~1e-6 asymmetry of inv(SPD)):
//   q[b,c] = x^T a x - 2 x^T (a m_c) + m_c^T (a m_c)
// G' = a*m (MFMA), t[c] = m_c . G'[:,c] (fp32), S' = X*G', xax via H = X*a^T.
__global__ __launch_bounds__(512) void fused_kernel(
    const float* __restrict__ X, const float* __restrict__ means,
    const float* __restrict__ alpha, float* __restrict__ out) {
    __shared__ __align__(16) unsigned char AL[Dn * 256];      // 32768B: bf16 alpha, swizzled
    __shared__ __align__(16) unsigned char MN[Dn * 258 * 2];  // 66048B: bf16 means; later G'
    __shared__ float TL[Cn];                                   // t[c]
    __shared__ float SMIN[8][16];
    __shared__ float SXAX[8][16];

    const int tid = threadIdx.x;
    const int w = tid >> 6;          // wave 0..7
    const int lane = tid & 63;
    const int l15 = lane & 15;
    const int lh = lane >> 4;        // 0..3
    const int b0 = blockIdx.x * 16;
    unsigned short* mn16 = (unsigned short*)MN;

    // ---------- Phase A: stage alpha (swizzled rows) + means (row-major) as bf16 ----------
    {
        const float4* a4 = (const float4*)alpha;
        #pragma unroll
        for (int i = 0; i < 8; ++i) {
            int idx4 = tid + i * 512;            // 0..4095
            int d = idx4 >> 5, e0 = (idx4 & 31) << 2;
            float4 v = a4[idx4];
            unsigned char* p = AL + SWZ_OFF(d, e0);   // e0*2 % 8 == 0 -> 4B aligned
            *(unsigned*)p = pk2(v.x, v.y);
            *(unsigned*)(p + 4) = pk2(v.z, v.w);
        }
        const float4* m4 = (const float4*)means;
        #pragma unroll
        for (int i = 0; i < 16; ++i) {
            int idx4 = tid + i * 512;            // 0..8191
            int d = idx4 >> 6, c0 = (idx4 & 63) << 2;
            unsigned* p = (unsigned*)&mn16[MN_IDX(d, c0)];
            float4 v = m4[idx4];
            p[0] = pk2(v.x, v.y);
            p[1] = pk2(v.z, v.w);
        }
    }
    __syncthreads();

    // ---------- Phase C: G'-GEMM  G'[128x256] = alpha * means  (wave w: cols 32w..32w+31) ----------
    f32x4 gacc[2][8];
    #pragma unroll
    for (int j = 0; j < 2; ++j)
        #pragma unroll
        for (int mt = 0; mt < 8; ++mt) gacc[j][mt] = (f32x4){0.f, 0.f, 0.f, 0.f};

    #pragma unroll
    for (int k0 = 0; k0 < 4; ++k0) {
        bf16x8 bj[2];
        #pragma unroll
        for (int j = 0; j < 2; ++j) {
            const int c = 32 * w + 16 * j + l15;
            bf16x8 b;
            #pragma unroll
            for (int i = 0; i < 8; ++i)
                b[i] = (short)mn16[MN_IDX(32 * k0 + 8 * lh + i, c)];  // conflict-free banks
            bj[j] = b;
        }
        #pragma unroll
        for (int mt = 0; mt < 8; ++mt) {
            bf16x8 a = *(const bf16x8*)(AL + SWZ_OFF(16 * mt + l15, 32 * k0 + 8 * lh));
            #pragma unroll
            for (int j = 0; j < 2; ++j)
                gacc[j][mt] = __builtin_amdgcn_mfma_f32_16x16x32_bf16(a, bj[j], gacc[j][mt], 0, 0, 0);
        }
    }

    // ---------- Phase D: t[c] = sum_d m[d][c] * G'[d][c]  (from C-regs, fp32) ----------
    {
        float tp[2];
        #pragma unroll
        for (int j = 0; j < 2; ++j) {
            const int c = 32 * w + 16 * j + l15;
            float v = 0.f;
            #pragma unroll
            for (int mt = 0; mt < 8; ++mt)
                #pragma unroll
                for (int r = 0; r < 4; ++r)
                    v = fmaf(bfu2f(mn16[MN_IDX(16 * mt + 4 * lh + r, c)]), gacc[j][mt][r], v);
            v += __shfl_xor(v, 16);   // reduce across lh (lanes share l15)
            v += __shfl_xor(v, 32);
            tp[j] = v;
        }
        if (lane < 16) {
            TL[32 * w + lane] = tp[0];
            TL[32 * w + 16 + lane] = tp[1];
        }
    }
    __syncthreads();   // everyone done READING means before overwrite

    // ---------- Phase E: write G' (bf16, swizzled col-major [c][d]) into MN region ----------
    #pragma unroll
    for (int j = 0; j < 2; ++j) {
        const int c = 32 * w + 16 * j + l15;
        #pragma unroll
        for (int mt = 0; mt < 8; ++mt)
            #pragma unroll
            for (int r0 = 0; r0 < 4; r0 += 2) {
                const int d = 16 * mt + 4 * lh + r0;          // 2d % 4 == 0 -> u32 ok
                *(unsigned*)(MN + SWZ_OFF(c, d)) =
                    pk2(gacc[j][mt][r0], gacc[j][mt][r0 + 1]);
            }
    }
    __syncthreads();

    // ---------- Phase F: main GEMM [X | augmented] -- wave w: tiles 3w..3w+2 of 24 ----------
    // tiles 0..15: S'-cols (G' from MN region); tiles 16..23: H-cols (alpha rows -> X*a^T).
    bf16x8 af[4];
    {
        const float* xrow = X + (b0 + l15) * Dn;
        #pragma unroll
        for (int k0 = 0; k0 < 4; ++k0) {
            const float4* p = (const float4*)(xrow + 32 * k0 + 8 * lh);
            float4 x0 = p[0], x1 = p[1];
            bf16x8 a;
            a[0] = (short)f2bfu(x0.x); a[1] = (short)f2bfu(x0.y);
            a[2] = (short)f2bfu(x0.z); a[3] = (short)f2bfu(x0.w);
            a[4] = (short)f2bfu(x1.x); a[5] = (short)f2bfu(x1.y);
            a[6] = (short)f2bfu(x1.z); a[7] = (short)f2bfu(x1.w);
            af[k0] = a;
        }
    }
    bf16x8 bf3[3][4];
    #pragma unroll
    for (int j2 = 0; j2 < 3; ++j2) {
        const int tg = 3 * w + j2;
        const unsigned char* base = (tg < 16) ? (const unsigned char*)MN : (const unsigned char*)AL;
        const int rowc = (tg < 16) ? (16 * tg + l15) : (16 * (tg - 16) + l15);
        #pragma unroll
        for (int k0 = 0; k0 < 4; ++k0)
            bf3[j2][k0] = *(const bf16x8*)(base + SWZ_OFF(rowc, 32 * k0 + 8 * lh));
    }
    f32x4 macc[3];
    #pragma unroll
    for (int j2 = 0; j2 < 3; ++j2) macc[j2] = (f32x4){0.f, 0.f, 0.f, 0.f};
    #pragma unroll
    for (int k0 = 0; k0 < 4; ++k0)
        #pragma unroll
        for (int j2 = 0; j2 < 3; ++j2)
            macc[j2] = __builtin_amdgcn_mfma_f32_16x16x32_bf16(af[k0], bf3[j2][k0], macc[j2], 0, 0, 0);

    // epilogue: C layout col=lane&15, row=4*(lane>>4)+reg
    {
        float mr[4], px[4];
        #pragma unroll
        for (int r = 0; r < 4; ++r) { mr[r] = 1e30f; px[r] = 0.f; }
        #pragma unroll
        for (int j2 = 0; j2 < 3; ++j2) {
            const int tg = 3 * w + j2;
            if (tg < 16) {
                float tc = TL[16 * tg + l15];
                #pragma unroll
                for (int r = 0; r < 4; ++r)
                    mr[r] = fminf(mr[r], tc - 2.f * macc[j2][r]);   // -2 x^T (a m_c)
            } else {
                const int dp = 16 * (tg - 16) + l15;
                #pragma unroll
                for (int r = 0; r < 4; ++r)
                    px[r] = fmaf(macc[j2][r], X[(b0 + 4 * lh + r) * Dn + dp], px[r]);
            }
        }
        #pragma unroll
        for (int r = 0; r < 4; ++r) {
            #pragma unroll
            for (int m = 1; m < 16; m <<= 1) {
                mr[r] = fminf(mr[r], __shfl_xor(mr[r], m));
                px[r] += __shfl_xor(px[r], m);
            }
        }
        if (l15 == 0) {
            #pragma unroll
            for (int r = 0; r < 4; ++r) {
                SMIN[w][4 * lh + r] = mr[r];
                SXAX[w][4 * lh + r] = px[r];
            }
        }
    }
    __syncthreads();

    if (tid < 16) {
        float mnv = 1e30f, xa = 0.f;
        #pragma unroll
        for (int w8 = 0; w8 < 8; ++w8) {
            mnv = fminf(mnv, SMIN[w8][tid]);
            xa += SXAX[w8][tid];
        }
        out[b0 + tid] = xa + mnv;   // xa = x^T a x (exact via X.(X a^T))
    }
}

extern "C" void kernel_launch(void* const* d_in, const int* in_sizes, int n_in,
                              void* d_out, int out_size, void* d_ws, size_t ws_size,
                              hipStream_t stream) {
    const float* X     = (const float*)d_in[0];
    const float* means = (const float*)d_in[1];
    const float* alpha = (const float*)d_in[2];
    float* out = (float*)d_out;
    fused_kernel<<<Bn / 16, 512, 0, stream>>>(X, means, alpha, out);
}

// Round 7
// 13.493 us; speedup vs baseline: 1.7576x; 1.0725x over previous
//
#include <hip/hip_runtime.h>
#include <hip/hip_bf16.h>

constexpr int Bn = 4096;
constexpr int Dn = 128;
constexpr int Cn = 256;

typedef __attribute__((ext_vector_type(8))) short bf16x8;  // 8 bf16 = 4 VGPR
typedef __attribute__((ext_vector_type(4))) float f32x4;

static __device__ inline unsigned short f2bfu(float f) {
    __hip_bfloat16 h = __float2bfloat16(f);
    return *reinterpret_cast<unsigned short*>(&h);
}
static __device__ inline float bfu2f(unsigned short u) {
    __hip_bfloat16 h = *reinterpret_cast<__hip_bfloat16*>(&u);
    return __bfloat162float(h);
}
static __device__ inline unsigned pk2(float x, float y) {
    return (unsigned)f2bfu(x) | ((unsigned)f2bfu(y) << 16);
}

// XOR-swizzled byte offset for 256B-row bf16 tiles:
//   row-major [R][128] bf16; lane-varying-row b128 reads become conflict-optimal.
#define SWZ_OFF(row, e) ((row) * 256 + ((((e) * 2)) ^ (((row) & 7) << 4)))

// Single fused kernel: 256 blocks x 512 threads (8 waves), block = 16 rows of X.
//   q[b,c] = x^T a x - 2 x^T (a m_c) + m_c^T (a m_c)
// G' = a*m (MFMA), t[c] = m_c . G'[:,c] (fp32), S' = X*G', xax via H = X*a^T.
// means staged TRANSPOSED: MT[c][d] bf16 swizzled -> all its reads are b128/b64.
__global__ __launch_bounds__(512) void fused_kernel(
    const float* __restrict__ X, const float* __restrict__ means,
    const float* __restrict__ alpha, float* __restrict__ out) {
    __shared__ __align__(16) unsigned char AL[Dn * 256];  // 32768B: bf16 alpha, swizzled
    __shared__ __align__(16) unsigned char MT[Cn * 256];  // 65536B: bf16 means^T; later G'
    __shared__ float TL[Cn];                               // t[c]
    __shared__ float SMIN[8][16];
    __shared__ float SXAX[8][16];

    const int tid = threadIdx.x;
    const int w = tid >> 6;          // wave 0..7
    const int lane = tid & 63;
    const int l15 = lane & 15;
    const int lh = lane >> 4;        // 0..3
    const int b0 = blockIdx.x * 16;

    // ---------- Phase A: stage alpha (swizzled rows) + means^T (4x4 reg transpose) ----------
    {
        const float4* a4 = (const float4*)alpha;
        #pragma unroll
        for (int i = 0; i < 8; ++i) {
            int idx4 = tid + i * 512;            // 0..4095
            int d = idx4 >> 5, e0 = (idx4 & 31) << 2;
            float4 v = a4[idx4];
            unsigned char* p = AL + SWZ_OFF(d, e0);   // e0*2 % 8 == 0 -> 4B aligned
            *(unsigned*)p = pk2(v.x, v.y);
            *(unsigned*)(p + 4) = pk2(v.z, v.w);
        }
        // means^T: wave w covers c in [32w,32w+32); lane: c-block = l&7, d-block = l>>3 (+8i)
        const int cb = 8 * w + (lane & 7);       // 0..63 (c = 4cb..4cb+3)
        const int db0 = lane >> 3;               // 0..7
        #pragma unroll
        for (int i = 0; i < 4; ++i) {
            const int db = db0 + 8 * i;          // 0..31  (d = 4db..4db+3)
            float4 v0 = *(const float4*)&means[(4 * db + 0) * Cn + 4 * cb];
            float4 v1 = *(const float4*)&means[(4 * db + 1) * Cn + 4 * cb];
            float4 v2 = *(const float4*)&means[(4 * db + 2) * Cn + 4 * cb];
            float4 v3 = *(const float4*)&means[(4 * db + 3) * Cn + 4 * cb];
            uint2 pk;
            pk.x = pk2(v0.x, v1.x); pk.y = pk2(v2.x, v3.x);
            *(uint2*)(MT + SWZ_OFF(4 * cb + 0, 4 * db)) = pk;
            pk.x = pk2(v0.y, v1.y); pk.y = pk2(v2.y, v3.y);
            *(uint2*)(MT + SWZ_OFF(4 * cb + 1, 4 * db)) = pk;
            pk.x = pk2(v0.z, v1.z); pk.y = pk2(v2.z, v3.z);
            *(uint2*)(MT + SWZ_OFF(4 * cb + 2, 4 * db)) = pk;
            pk.x = pk2(v0.w, v1.w); pk.y = pk2(v2.w, v3.w);
            *(uint2*)(MT + SWZ_OFF(4 * cb + 3, 4 * db)) = pk;
        }
    }
    __syncthreads();

    // ---------- Phase C: G'-GEMM  G'[128x256] = alpha * means  (wave w: cols 32w..32w+31) ----------
    f32x4 gacc[2][8];
    #pragma unroll
    for (int j = 0; j < 2; ++j)
        #pragma unroll
        for (int mt = 0; mt < 8; ++mt) gacc[j][mt] = (f32x4){0.f, 0.f, 0.f, 0.f};

    #pragma unroll
    for (int k0 = 0; k0 < 4; ++k0) {
        bf16x8 bj[2];
        #pragma unroll
        for (int j = 0; j < 2; ++j) {
            const int c = 32 * w + 16 * j + l15;
            bj[j] = *(const bf16x8*)(MT + SWZ_OFF(c, 32 * k0 + 8 * lh));  // b128
        }
        #pragma unroll
        for (int mt = 0; mt < 8; ++mt) {
            bf16x8 a = *(const bf16x8*)(AL + SWZ_OFF(16 * mt + l15, 32 * k0 + 8 * lh));
            #pragma unroll
            for (int j = 0; j < 2; ++j)
                gacc[j][mt] = __builtin_amdgcn_mfma_f32_16x16x32_bf16(a, bj[j], gacc[j][mt], 0, 0, 0);
        }
    }

    // ---------- Phase D: t[c] = sum_d m[d][c] * G'[d][c]  (b64 reads from MT, fp32) ----------
    {
        float tp[2];
        #pragma unroll
        for (int j = 0; j < 2; ++j) {
            const int c = 32 * w + 16 * j + l15;
            float v = 0.f;
            #pragma unroll
            for (int mt = 0; mt < 8; ++mt) {
                uint2 pk = *(const uint2*)(MT + SWZ_OFF(c, 16 * mt + 4 * lh));
                v = fmaf(bfu2f((unsigned short)(pk.x & 0xffffu)), gacc[j][mt][0], v);
                v = fmaf(bfu2f((unsigned short)(pk.x >> 16)),     gacc[j][mt][1], v);
                v = fmaf(bfu2f((unsigned short)(pk.y & 0xffffu)), gacc[j][mt][2], v);
                v = fmaf(bfu2f((unsigned short)(pk.y >> 16)),     gacc[j][mt][3], v);
            }
            v += __shfl_xor(v, 16);   // reduce across lh (lanes share l15)
            v += __shfl_xor(v, 32);
            tp[j] = v;
        }
        if (lane < 16) {
            TL[32 * w + lane] = tp[0];
            TL[32 * w + 16 + lane] = tp[1];
        }
    }
    __syncthreads();   // everyone done READING MT before overwrite

    // ---------- Phase E: overwrite MT with G' (bf16, same swizzled [c][d] layout) ----------
    #pragma unroll
    for (int j = 0; j < 2; ++j) {
        const int c = 32 * w + 16 * j + l15;
        #pragma unroll
        for (int mt = 0; mt < 8; ++mt) {
            uint2 pk;
            pk.x = pk2(gacc[j][mt][0], gacc[j][mt][1]);
            pk.y = pk2(gacc[j][mt][2], gacc[j][mt][3]);
            *(uint2*)(MT + SWZ_OFF(c, 16 * mt + 4 * lh)) = pk;   // d = 16mt+4lh..+3
        }
    }
    __syncthreads();

    // ---------- Phase F: main GEMM [X | augmented] -- wave w: tiles 3w..3w+2 of 24 ----------
    // tiles 0..15: S'-cols (G' rows from MT); tiles 16..23: H-cols (alpha rows -> X*a^T).
    bf16x8 af[4];
    {
        const float* xrow = X + (b0 + l15) * Dn;
        #pragma unroll
        for (int k0 = 0; k0 < 4; ++k0) {
            const float4* p = (const float4*)(xrow + 32 * k0 + 8 * lh);
            float4 x0 = p[0], x1 = p[1];
            bf16x8 a;
            a[0] = (short)f2bfu(x0.x); a[1] = (short)f2bfu(x0.y);
            a[2] = (short)f2bfu(x0.z); a[3] = (short)f2bfu(x0.w);
            a[4] = (short)f2bfu(x1.x); a[5] = (short)f2bfu(x1.y);
            a[6] = (short)f2bfu(x1.z); a[7] = (short)f2bfu(x1.w);
            af[k0] = a;
        }
    }
    bf16x8 bf3[3][4];
    #pragma unroll
    for (int j2 = 0; j2 < 3; ++j2) {
        const int tg = 3 * w + j2;
        const unsigned char* base = (tg < 16) ? (const unsigned char*)MT : (const unsigned char*)AL;
        const int rowc = (tg < 16) ? (16 * tg + l15) : (16 * (tg - 16) + l15);
        #pragma unroll
        for (int k0 = 0; k0 < 4; ++k0)
            bf3[j2][k0] = *(const bf16x8*)(base + SWZ_OFF(rowc, 32 * k0 + 8 * lh));
    }
    f32x4 macc[3];
    #pragma unroll
    for (int j2 = 0; j2 < 3; ++j2) macc[j2] = (f32x4){0.f, 0.f, 0.f, 0.f};
    #pragma unroll
    for (int k0 = 0; k0 < 4; ++k0)
        #pragma unroll
        for (int j2 = 0; j2 < 3; ++j2)
            macc[j2] = __builtin_amdgcn_mfma_f32_16x16x32_bf16(af[k0], bf3[j2][k0], macc[j2], 0, 0, 0);

    // epilogue: C layout col=lane&15, row=4*(lane>>4)+reg
    {
        float mr[4], px[4];
        #pragma unroll
        for (int r = 0; r < 4; ++r) { mr[r] = 1e30f; px[r] = 0.f; }
        #pragma unroll
        for (int j2 = 0; j2 < 3; ++j2) {
            const int tg = 3 * w + j2;
            if (tg < 16) {
                float tc = TL[16 * tg + l15];
                #pragma unroll
                for (int r = 0; r < 4; ++r)
                    mr[r] = fminf(mr[r], tc - 2.f * macc[j2][r]);   // -2 x^T (a m_c)
            } else {
                const int dp = 16 * (tg - 16) + l15;
                #pragma unroll
                for (int r = 0; r < 4; ++r)
                    px[r] = fmaf(macc[j2][r], X[(b0 + 4 * lh + r) * Dn + dp], px[r]);
            }
        }
        #pragma unroll
        for (int r = 0; r < 4; ++r) {
            #pragma unroll
            for (int m = 1; m < 16; m <<= 1) {
                mr[r] = fminf(mr[r], __shfl_xor(mr[r], m));
                px[r] += __shfl_xor(px[r], m);
            }
        }
        if (l15 == 0) {
            #pragma unroll
            for (int r = 0; r < 4; ++r) {
                SMIN[w][4 * lh + r] = mr[r];
                SXAX[w][4 * lh + r] = px[r];
            }
        }
    }
    __syncthreads();

    if (tid < 16) {
        float mnv = 1e30f, xa = 0.f;
        #pragma unroll
        for (int w8 = 0; w8 < 8; ++w8) {
            mnv = fminf(mnv, SMIN[w8][tid]);
            xa += SXAX[w8][tid];
        }
        out[b0 + tid] = xa + mnv;   // xa = x^T a x (exact via X.(X a^T))
    }
}

extern "C" void kernel_launch(void* const* d_in, const int* in_sizes, int n_in,
                              void* d_out, int out_size, void* d_ws, size_t ws_size,
                              hipStream_t stream) {
    const float* X     = (const float*)d_in[0];
    const float* means = (const float*)d_in[1];
    const float* alpha = (const float*)d_in[2];
    float* out = (float*)d_out;
    fused_kernel<<<Bn / 16, 512, 0, stream>>>(X, means, alpha, out);
}

// Round 8
// 11.726 us; speedup vs baseline: 2.0224x; 1.1507x over previous
//
#include <hip/hip_runtime.h>
#include <hip/hip_bf16.h>

constexpr int Bn = 4096;
constexpr int Dn = 128;
constexpr int Cn = 256;

typedef __attribute__((ext_vector_type(8))) short bf16x8;  // 8 bf16 = 4 VGPR
typedef __attribute__((ext_vector_type(4))) float f32x4;

static __device__ inline unsigned short f2bfu(float f) {
    __hip_bfloat16 h = __float2bfloat16(f);
    return *reinterpret_cast<unsigned short*>(&h);
}
static __device__ inline float bfu2f(unsigned short u) {
    __hip_bfloat16 h = *reinterpret_cast<__hip_bfloat16*>(&u);
    return __bfloat162float(h);
}
static __device__ inline unsigned pk2(float x, float y) {
    return (unsigned)f2bfu(x) | ((unsigned)f2bfu(y) << 16);
}

// XOR-swizzled byte offset for 256B-row bf16 tiles (rows of 128 bf16):
#define SWZ_OFF(row, e) ((row) * 256 + ((((e) * 2)) ^ (((row) & 7) << 4)))

// Single fused kernel: 256 blocks x 512 threads (8 waves), block = 16 rows of X.
//   q[b,c] = x^T a x - 2 x^T (a m_c) + m_c^T (a m_c)
// Phase C: G' = a*means (64 MFMA/wave) + H-tile (a*X^T, 4 MFMA/wave, rows 16w..)
//   -> xax partial per wave via 1 b64 + 4 FMA + shfl  (SXAX[w])
// Phase D: t[c] = m_c . G'[:,c]  (fp32, wave-local MT cols -> tp[2] registers)
// Phase E: overwrite MT with bf16 G' (wave-local cols, no barrier needed)
// Phase F: S' = X*G' (2 tiles/wave, A-frags from XL), min epilogue uses tp[j2].
__global__ __launch_bounds__(512) void fused_kernel(
    const float* __restrict__ X, const float* __restrict__ means,
    const float* __restrict__ alpha, float* __restrict__ out) {
    __shared__ __align__(16) unsigned char AL[Dn * 256];  // 32768B: bf16 alpha, swizzled
    __shared__ __align__(16) unsigned char MT[Cn * 256];  // 65536B: bf16 means^T; later G'
    __shared__ __align__(16) unsigned char XL[16 * 256];  // 4096B:  bf16 X-tile, swizzled
    __shared__ float SMIN[8][16];
    __shared__ float SXAX[8][16];

    const int tid = threadIdx.x;
    const int w = tid >> 6;          // wave 0..7
    const int lane = tid & 63;
    const int l15 = lane & 15;
    const int lh = lane >> 4;        // 0..3
    const int b0 = blockIdx.x * 16;

    // ---------- Phase A: stage alpha, X-tile, means^T (all bf16, swizzled) ----------
    {
        // X-tile: 2048 floats, 1 float4 per thread
        {
            float4 v = ((const float4*)(X + b0 * Dn))[tid];
            const int b = tid >> 5;              // 32 float4 per row
            const int e0 = (tid & 31) << 2;
            uint2 pk;
            pk.x = pk2(v.x, v.y); pk.y = pk2(v.z, v.w);
            *(uint2*)(XL + SWZ_OFF(b, e0)) = pk;
        }
        const float4* a4 = (const float4*)alpha;
        #pragma unroll
        for (int i = 0; i < 8; ++i) {
            int idx4 = tid + i * 512;            // 0..4095
            int d = idx4 >> 5, e0 = (idx4 & 31) << 2;
            float4 v = a4[idx4];
            unsigned char* p = AL + SWZ_OFF(d, e0);
            *(unsigned*)p = pk2(v.x, v.y);
            *(unsigned*)(p + 4) = pk2(v.z, v.w);
        }
        // means^T: wave w covers c in [32w,32w+32) (wave-local = its own GEMM cols)
        const int cb = 8 * w + (lane & 7);       // c = 4cb..4cb+3
        const int db0 = lane >> 3;               // 0..7
        #pragma unroll
        for (int i = 0; i < 4; ++i) {
            const int db = db0 + 8 * i;          // d = 4db..4db+3
            float4 v0 = *(const float4*)&means[(4 * db + 0) * Cn + 4 * cb];
            float4 v1 = *(const float4*)&means[(4 * db + 1) * Cn + 4 * cb];
            float4 v2 = *(const float4*)&means[(4 * db + 2) * Cn + 4 * cb];
            float4 v3 = *(const float4*)&means[(4 * db + 3) * Cn + 4 * cb];
            uint2 pk;
            pk.x = pk2(v0.x, v1.x); pk.y = pk2(v2.x, v3.x);
            *(uint2*)(MT + SWZ_OFF(4 * cb + 0, 4 * db)) = pk;
            pk.x = pk2(v0.y, v1.y); pk.y = pk2(v2.y, v3.y);
            *(uint2*)(MT + SWZ_OFF(4 * cb + 1, 4 * db)) = pk;
            pk.x = pk2(v0.z, v1.z); pk.y = pk2(v2.z, v3.z);
            *(uint2*)(MT + SWZ_OFF(4 * cb + 2, 4 * db)) = pk;
            pk.x = pk2(v0.w, v1.w); pk.y = pk2(v2.w, v3.w);
            *(uint2*)(MT + SWZ_OFF(4 * cb + 3, 4 * db)) = pk;
        }
    }
    __syncthreads();

    // ---------- Phase C: G'-GEMM (wave cols 32w..32w+31) + H-tile (rows 16w..16w+15) ----------
    f32x4 gacc[2][8];
    #pragma unroll
    for (int j = 0; j < 2; ++j)
        #pragma unroll
        for (int mt = 0; mt < 8; ++mt) gacc[j][mt] = (f32x4){0.f, 0.f, 0.f, 0.f};
    f32x4 xacc = (f32x4){0.f, 0.f, 0.f, 0.f};

    #pragma unroll
    for (int k0 = 0; k0 < 4; ++k0) {
        bf16x8 bj[2];
        #pragma unroll
        for (int j = 0; j < 2; ++j) {
            const int c = 32 * w + 16 * j + l15;
            bj[j] = *(const bf16x8*)(MT + SWZ_OFF(c, 32 * k0 + 8 * lh));
        }
        #pragma unroll
        for (int mt = 0; mt < 8; ++mt) {
            bf16x8 a = *(const bf16x8*)(AL + SWZ_OFF(16 * mt + l15, 32 * k0 + 8 * lh));
            #pragma unroll
            for (int j = 0; j < 2; ++j)
                gacc[j][mt] = __builtin_amdgcn_mfma_f32_16x16x32_bf16(a, bj[j], gacc[j][mt], 0, 0, 0);
        }
        // H-tile: C[d][b] = sum_e a[d][e] X[b][e]; A = AL rows 16w.., B = XL rows
        {
            bf16x8 a = *(const bf16x8*)(AL + SWZ_OFF(16 * w + l15, 32 * k0 + 8 * lh));
            bf16x8 bx = *(const bf16x8*)(XL + SWZ_OFF(l15, 32 * k0 + 8 * lh));
            xacc = __builtin_amdgcn_mfma_f32_16x16x32_bf16(a, bx, xacc, 0, 0, 0);
        }
    }

    // xax partial: lane (b=l15, lh) holds H[16w+4lh+r][b]; dot with x[b][same d]
    {
        uint2 pk = *(const uint2*)(XL + SWZ_OFF(l15, 16 * w + 4 * lh));
        float v = bfu2f((unsigned short)(pk.x & 0xffffu)) * xacc[0];
        v = fmaf(bfu2f((unsigned short)(pk.x >> 16)),     xacc[1], v);
        v = fmaf(bfu2f((unsigned short)(pk.y & 0xffffu)), xacc[2], v);
        v = fmaf(bfu2f((unsigned short)(pk.y >> 16)),     xacc[3], v);
        v += __shfl_xor(v, 16);
        v += __shfl_xor(v, 32);
        if (lane < 16) SXAX[w][lane] = v;
    }

    // ---------- Phase D: t[c] (wave-local MT cols, kept in registers) ----------
    float tp[2];
    #pragma unroll
    for (int j = 0; j < 2; ++j) {
        const int c = 32 * w + 16 * j + l15;
        float v = 0.f;
        #pragma unroll
        for (int mt = 0; mt < 8; ++mt) {
            uint2 pk = *(const uint2*)(MT + SWZ_OFF(c, 16 * mt + 4 * lh));
            v = fmaf(bfu2f((unsigned short)(pk.x & 0xffffu)), gacc[j][mt][0], v);
            v = fmaf(bfu2f((unsigned short)(pk.x >> 16)),     gacc[j][mt][1], v);
            v = fmaf(bfu2f((unsigned short)(pk.y & 0xffffu)), gacc[j][mt][2], v);
            v = fmaf(bfu2f((unsigned short)(pk.y >> 16)),     gacc[j][mt][3], v);
        }
        v += __shfl_xor(v, 16);   // all lanes end with full sum (butterfly)
        v += __shfl_xor(v, 32);
        tp[j] = v;
    }

    // ---------- Phase E: overwrite MT with G' (wave-local cols; no barrier vs D) ----------
    #pragma unroll
    for (int j = 0; j < 2; ++j) {
        const int c = 32 * w + 16 * j + l15;
        #pragma unroll
        for (int mt = 0; mt < 8; ++mt) {
            uint2 pk;
            pk.x = pk2(gacc[j][mt][0], gacc[j][mt][1]);
            pk.y = pk2(gacc[j][mt][2], gacc[j][mt][3]);
            *(uint2*)(MT + SWZ_OFF(c, 16 * mt + 4 * lh)) = pk;
        }
    }
    __syncthreads();

    // ---------- Phase F: S' = X*G' -- wave w: tiles 2w, 2w+1 of 16 ----------
    bf16x8 af[4];
    #pragma unroll
    for (int k0 = 0; k0 < 4; ++k0)
        af[k0] = *(const bf16x8*)(XL + SWZ_OFF(l15, 32 * k0 + 8 * lh));
    bf16x8 bf2[2][4];
    #pragma unroll
    for (int j2 = 0; j2 < 2; ++j2) {
        const int rowc = 16 * (2 * w + j2) + l15;
        #pragma unroll
        for (int k0 = 0; k0 < 4; ++k0)
            bf2[j2][k0] = *(const bf16x8*)(MT + SWZ_OFF(rowc, 32 * k0 + 8 * lh));
    }
    f32x4 macc[2];
    #pragma unroll
    for (int j2 = 0; j2 < 2; ++j2) macc[j2] = (f32x4){0.f, 0.f, 0.f, 0.f};
    #pragma unroll
    for (int k0 = 0; k0 < 4; ++k0)
        #pragma unroll
        for (int j2 = 0; j2 < 2; ++j2)
            macc[j2] = __builtin_amdgcn_mfma_f32_16x16x32_bf16(af[k0], bf2[j2][k0], macc[j2], 0, 0, 0);

    // epilogue: C layout col=lane&15 (=c within tile), row=4*lh+reg (=b)
    {
        float mr[4];
        #pragma unroll
        for (int r = 0; r < 4; ++r) mr[r] = 1e30f;
        #pragma unroll
        for (int j2 = 0; j2 < 2; ++j2) {
            const float tc = tp[j2];   // t for col 32w+16j2+l15 == this tile's col
            #pragma unroll
            for (int r = 0; r < 4; ++r)
                mr[r] = fminf(mr[r], tc - 2.f * macc[j2][r]);   // -2 x^T (a m_c)
        }
        #pragma unroll
        for (int r = 0; r < 4; ++r) {
            #pragma unroll
            for (int m = 1; m < 16; m <<= 1)
                mr[r] = fminf(mr[r], __shfl_xor(mr[r], m));
        }
        if (l15 == 0)
            #pragma unroll
            for (int r = 0; r < 4; ++r) SMIN[w][4 * lh + r] = mr[r];
    }
    __syncthreads();

    if (tid < 16) {
        float mnv = 1e30f, xa = 0.f;
        #pragma unroll
        for (int w8 = 0; w8 < 8; ++w8) {
            mnv = fminf(mnv, SMIN[w8][tid]);
            xa += SXAX[w8][tid];
        }
        out[b0 + tid] = xa + mnv;   // xa = x^T a x
    }
}

extern "C" void kernel_launch(void* const* d_in, const int* in_sizes, int n_in,
                              void* d_out, int out_size, void* d_ws, size_t ws_size,
                              hipStream_t stream) {
    const float* X     = (const float*)d_in[0];
    const float* means = (const float*)d_in[1];
    const float* alpha = (const float*)d_in[2];
    float* out = (float*)d_out;
    fused_kernel<<<Bn / 16, 512, 0, stream>>>(X, means, alpha, out);
}